// Round 8
// baseline (821.061 us; speedup 1.0000x reference)
//
#include <hip/hip_runtime.h>
#include <math.h>

// Problem constants
#define B_    2
#define DDIM  160
#define HDIM  160
#define WDIM  160
#define DHW   (DDIM*HDIM*WDIM)      // 4,096,000
#define NVOX  (B_*DHW)              // 8,192,000
#define NGRP  (NVOX/4)              // 2,048,000 float4 groups
#define ITERS 8

#define SMOOTHF 1e-5
#define EPSF    1e-6
#define W_CL    0.5

// Reduction partials
#define NB1 2048
#define NQ1 10
#define NB2 2048
#define NQ2 4

// Bitpacked y volume
#define NROWS (B_*DDIM*HDIM)        // 51,200 rows
#define YW    8                     // words per row (5 used, 3 pad)
#define NYW   (NROWS*YW)            // 409,600 words

// Fused-iteration tiling
#define TH 16
#define TD 16
#define WP (WDIM+4)                 // padded LDS row stride (keeps 16B align, spreads banks)
#define PH_BLOCKS (B_*(HDIM/TH)*(DDIM/TD))   // 200
#define Y_BLOCKS  (NROWS/256)                 // 200
#define F_BLOCKS  (PH_BLOCKS + Y_BLOCKS)      // 400

// ws layout (bytes)
#define OFF_P1 0
#define OFF_P2 (NB1*NQ1*8)          // 163,840
#define HEADER_BYTES 262144         // 256 KiB

// ---------------- reduction helpers ----------------

__device__ inline double wave_reduce(double v) {
    #pragma unroll
    for (int off = 32; off > 0; off >>= 1)
        v += __shfl_down(v, off, 64);
    return v;
}

template<int NQ>
__device__ inline void block_reduce_store(double* vals, double* out) {
    __shared__ double smem[NQ][4];
    int lane = threadIdx.x & 63;
    int wid  = threadIdx.x >> 6;
    #pragma unroll
    for (int q = 0; q < NQ; ++q) {
        double v = wave_reduce(vals[q]);
        if (lane == 0) smem[q][wid] = v;
    }
    __syncthreads();
    if (threadIdx.x == 0) {
        #pragma unroll
        for (int q = 0; q < NQ; ++q)
            out[q] = smem[q][0] + smem[q][1] + smem[q][2] + smem[q][3];
    }
}

// ---------------- pass 1: softmax / CE / dice partials / p_v ----------------

__global__ void init_kernel(const float* __restrict__ logits,
                            const int*   __restrict__ target,
                            float* __restrict__ porig,
                            double* __restrict__ partials)
{
    float facc[NQ1];
    #pragma unroll
    for (int q = 0; q < NQ1; ++q) facc[q] = 0.0f;
    // 0=ce, 1..3=intersect_c, 4..6=pred_sum_c, 7..9=targ_sum_c
    // per-thread accumulates at most 16 voxels -> f32 exact enough; f64 at block level

    int tid = blockIdx.x * blockDim.x + threadIdx.x;
    int stride = gridDim.x * blockDim.x;
    for (int g = tid; g < NGRP; g += stride) {
        int i = g * 4;
        int b = i / DHW;
        int s = i - b * DHW;
        const float* base = logits + (size_t)b * (3 * DHW) + s;
        float4 l0 = *(const float4*)(base);
        float4 l1 = *(const float4*)(base + DHW);
        float4 l2 = *(const float4*)(base + 2 * DHW);
        int4 tg = *(const int4*)(target + i);

        float pv[4];
        const float* a0 = (const float*)&l0;
        const float* a1 = (const float*)&l1;
        const float* a2 = (const float*)&l2;
        const int*   tt = (const int*)&tg;
        #pragma unroll
        for (int j = 0; j < 4; ++j) {
            float x0 = a0[j], x1 = a1[j], x2 = a2[j];
            float m  = fmaxf(x0, fmaxf(x1, x2));
            float e0 = __expf(x0 - m), e1 = __expf(x1 - m), e2 = __expf(x2 - m);
            float sum = e0 + e1 + e2;
            float inv = 1.0f / sum;
            float q0 = e0 * inv, q1 = e1 * inv, q2 = e2 * inv;
            int t = tt[j];
            float lt = (t == 0) ? x0 : ((t == 1) ? x1 : x2);
            float logp_t = (lt - m) - __logf(sum);
            facc[0] += -logp_t;
            facc[4] += q0; facc[5] += q1; facc[6] += q2;
            if (t == 0)      { facc[1] += q0; facc[7] += 1.0f; }
            else if (t == 1) { facc[2] += q1; facc[8] += 1.0f; }
            else             { facc[3] += q2; facc[9] += 1.0f; }
            float p = 1.0f - q0;
            pv[j] = fminf(fmaxf(p, 0.0f), 1.0f);
        }
        *(float4*)(porig + i) = make_float4(pv[0], pv[1], pv[2], pv[3]);
    }
    double acc[NQ1];
    #pragma unroll
    for (int q = 0; q < NQ1; ++q) acc[q] = (double)facc[q];
    block_reduce_store<NQ1>(acc, partials + (size_t)blockIdx.x * NQ1);
}

// ---------------- y bitpack init ----------------

__global__ void ybits_init(const int* __restrict__ target,
                           unsigned* __restrict__ yb)
{
    int tid = blockIdx.x * 256 + threadIdx.x;   // NYW threads exactly
    int k = tid % YW;
    int rowlin = tid / YW;
    unsigned word = 0u;
    if (k < 5) {
        const int* t = target + (size_t)rowlin * WDIM + k * 32;
        #pragma unroll
        for (int q = 0; q < 8; ++q) {
            int4 v = *(const int4*)(t + q * 4);
            if (v.x) word |= 1u << (q * 4 + 0);
            if (v.y) word |= 1u << (q * 4 + 1);
            if (v.z) word |= 1u << (q * 4 + 2);
            if (v.w) word |= 1u << (q * 4 + 3);
        }
    }
    yb[tid] = word;
}

// ---------------- bit-row helpers ----------------

__device__ inline void load_yrow(const unsigned* __restrict__ base, unsigned* r) {
    uint4 v = *(const uint4*)base;
    r[0] = v.x; r[1] = v.y; r[2] = v.z; r[3] = v.w; r[4] = base[4];
}

__device__ inline void werode_row(const unsigned* r, unsigned* out) {
    #pragma unroll
    for (int k = 0; k < 5; ++k) {
        unsigned l  = (r[k] << 1) | (k > 0 ? (r[k-1] >> 31) : 1u);
        unsigned rt = (r[k] >> 1) | (k < 4 ? (r[k+1] << 31) : 0x80000000u);
        out[k] = r[k] & l & rt;
    }
}

__device__ inline void wdilate_row(const unsigned* r, unsigned* out) {
    #pragma unroll
    for (int k = 0; k < 5; ++k) {
        unsigned l  = (r[k] << 1) | (k > 0 ? (r[k-1] >> 31) : 0u);
        unsigned rt = (r[k] >> 1) | (k < 4 ? (r[k+1] << 31) : 0u);
        out[k] = r[k] | l | rt;
    }
}

// ---------------- fused soft-skeleton iteration ----------------
// p-branch: one full erode+open+update iteration via D-plane streaming.
//   RM ring: row-min (W-reduce) of x planes, rows h0-2..h0+TH+1
//   B ring:  eroded planes (min 3x3 over RM plane/row), rows h0-1..h0+TH
//   OUT:     opened = max 3x3x3 over B, contour, x-update. Ping-pong x buffers.
// y-branch: one thread per output bit-row, full recompute stream (exact booleans).

__global__ __launch_bounds__(256) void fused_iter(
        const float* __restrict__ xsrc, float* __restrict__ xdst,
        const unsigned* __restrict__ ysrc, unsigned* __restrict__ ydst)
{
    if (blockIdx.x < PH_BLOCKS) {
        __shared__ float RM[3][TH+4][WP];
        __shared__ float BB[3][TH+2][WP];

        int bid = blockIdx.x;
        int dt  = bid % (DDIM/TD);
        int t1  = bid / (DDIM/TD);
        int ht  = t1 % (HDIM/TH);
        int vol = t1 / (HDIM/TH);
        int h0 = ht * TH, d0 = dt * TD;
        const float* X  = xsrc + (size_t)vol * DHW;
        float*       XO = xdst + (size_t)vol * DHW;

        int tid = threadIdx.x;
        int r   = tid / 10;          // row unit
        int seg = tid % 10;          // 16-wide column segment
        int w0  = seg * 16;

        for (int s = 0; s < TD + 4; ++s) {
            int p = d0 - 2 + s;               // x plane being staged
            // ---- phase RM: row-min of x plane p ----
            if (tid < (TH+4)*10 && (unsigned)p < (unsigned)DDIM) {
                int y = h0 - 2 + r;
                if ((unsigned)y < (unsigned)HDIM) {
                    const float* row = X + ((size_t)p * HDIM + y) * WDIM + w0;
                    float e[18];
                    float4 f;
                    f = *(const float4*)(row + 0);  e[1]=f.x;  e[2]=f.y;  e[3]=f.z;  e[4]=f.w;
                    f = *(const float4*)(row + 4);  e[5]=f.x;  e[6]=f.y;  e[7]=f.z;  e[8]=f.w;
                    f = *(const float4*)(row + 8);  e[9]=f.x;  e[10]=f.y; e[11]=f.z; e[12]=f.w;
                    f = *(const float4*)(row + 12); e[13]=f.x; e[14]=f.y; e[15]=f.z; e[16]=f.w;
                    e[0]  = (w0 > 0)          ? row[-1] : INFINITY;
                    e[17] = (w0 + 16 < WDIM)  ? row[16] : INFINITY;
                    float* o = &RM[(p+3)%3][r][w0];
                    #pragma unroll
                    for (int i = 0; i < 16; ++i)
                        o[i] = fminf(e[i], fminf(e[i+1], e[i+2]));
                }
            }
            __syncthreads();
            // ---- phase B: eroded plane e = p-1 (min over 3 planes x 3 rows of RM) ----
            int e = p - 1;
            if (s >= 2 && tid < (TH+2)*10 && (unsigned)e < (unsigned)DDIM) {
                int y = h0 - 1 + r;
                if ((unsigned)y < (unsigned)HDIM) {
                    float acc[16];
                    #pragma unroll
                    for (int i = 0; i < 16; ++i) acc[i] = INFINITY;
                    #pragma unroll
                    for (int dz = -1; dz <= 1; ++dz) {
                        int pp = e + dz;
                        if ((unsigned)pp >= (unsigned)DDIM) continue;
                        #pragma unroll
                        for (int dy = -1; dy <= 1; ++dy) {
                            int yy = y + dy;
                            if ((unsigned)yy >= (unsigned)HDIM) continue;
                            const float* src = &RM[(pp+3)%3][yy - (h0-2)][w0];
                            #pragma unroll
                            for (int i = 0; i < 16; ++i) acc[i] = fminf(acc[i], src[i]);
                        }
                    }
                    float* o = &BB[(e+3)%3][r][w0];
                    #pragma unroll
                    for (int i = 0; i < 16; ++i) o[i] = acc[i];
                }
            }
            __syncthreads();
            // ---- phase OUT: opened at dd = p-2, contour, update ----
            int dd = p - 2;
            if (s >= 4 && tid < TH*10) {
                int h = h0 + r;
                float opn[16];
                #pragma unroll
                for (int i = 0; i < 16; ++i) opn[i] = -INFINITY;
                #pragma unroll
                for (int dz = -1; dz <= 1; ++dz) {
                    int ee = dd + dz;
                    if ((unsigned)ee >= (unsigned)DDIM) continue;
                    #pragma unroll
                    for (int dy = -1; dy <= 1; ++dy) {
                        int yy = h + dy;
                        if ((unsigned)yy >= (unsigned)HDIM) continue;
                        const float* brow = &BB[(ee+3)%3][yy - (h0-1)][0];
                        float e2[18];
                        #pragma unroll
                        for (int i = 0; i < 16; ++i) e2[i+1] = brow[w0 + i];
                        e2[0]  = (w0 > 0)         ? brow[w0 - 1]  : -INFINITY;
                        e2[17] = (w0 + 16 < WDIM) ? brow[w0 + 16] : -INFINITY;
                        #pragma unroll
                        for (int i = 0; i < 16; ++i)
                            opn[i] = fmaxf(opn[i], fmaxf(e2[i], fmaxf(e2[i+1], e2[i+2])));
                    }
                }
                const float* ec = &BB[(dd+3)%3][r+1][w0];
                size_t idx = ((size_t)dd * HDIM + h) * WDIM + w0;
                #pragma unroll
                for (int q = 0; q < 4; ++q) {
                    float4 xv = *(const float4*)(X + idx + q*4);
                    float4 rs;
                    rs.x = fmaxf(xv.x - fmaxf(opn[q*4+0] - ec[q*4+0], 0.0f), 0.0f);
                    rs.y = fmaxf(xv.y - fmaxf(opn[q*4+1] - ec[q*4+1], 0.0f), 0.0f);
                    rs.z = fmaxf(xv.z - fmaxf(opn[q*4+2] - ec[q*4+2], 0.0f), 0.0f);
                    rs.w = fmaxf(xv.w - fmaxf(opn[q*4+3] - ec[q*4+3], 0.0f), 0.0f);
                    *(float4*)(XO + idx + q*4) = rs;
                }
            }
            __syncthreads();
        }
    } else {
        // ---------- y branch: one thread per output bit-row ----------
        int tid = (blockIdx.x - PH_BLOCKS) * 256 + threadIdx.x;  // 0..NROWS-1
        int h  = tid % HDIM;
        int t2 = tid / HDIM;
        int dd = t2 % DDIM;
        int b  = t2 / DDIM;
        const unsigned* YS = ysrc + (size_t)b * DDIM * HDIM * YW;

        unsigned EH[3][3][5];   // z-ring of H-eroded rows (rows y'=h-1..h+1)
        unsigned OPN[5] = {0u,0u,0u,0u,0u};
        unsigned EC[5]  = {0u,0u,0u,0u,0u};

        #pragma unroll
        for (int zi = 0; zi < 5; ++zi) {
            int z = dd - 2 + zi;
            if ((unsigned)z < (unsigned)DDIM) {
                unsigned RW[5][5];
                bool rwv[5];
                #pragma unroll
                for (int q = 0; q < 5; ++q) {
                    int yy = h - 2 + q;
                    rwv[q] = ((unsigned)yy < (unsigned)HDIM);
                    if (rwv[q]) {
                        unsigned xr[5];
                        load_yrow(YS + ((size_t)z * HDIM + yy) * YW, xr);
                        werode_row(xr, RW[q]);
                    }
                }
                #pragma unroll
                for (int j = 0; j < 3; ++j) {
                    unsigned acc[5] = {~0u,~0u,~0u,~0u,~0u};
                    #pragma unroll
                    for (int dy = -1; dy <= 1; ++dy) {
                        int q = j + dy + 1;
                        if (rwv[q]) {
                            #pragma unroll
                            for (int k = 0; k < 5; ++k) acc[k] &= RW[q][k];
                        }
                    }
                    #pragma unroll
                    for (int k = 0; k < 5; ++k) EH[zi%3][j][k] = acc[k];
                }
            } else {
                #pragma unroll
                for (int j = 0; j < 3; ++j)
                    #pragma unroll
                    for (int k = 0; k < 5; ++k) EH[zi%3][j][k] = ~0u;  // AND identity
            }
            if (zi >= 2) {
                int e = z - 1;   // e in dd-1..dd+1
                if ((unsigned)e < (unsigned)DDIM) {
                    #pragma unroll
                    for (int j = 0; j < 3; ++j) {
                        int yp = h - 1 + j;
                        if ((unsigned)yp >= (unsigned)HDIM) continue;
                        unsigned er[5], wd[5];
                        #pragma unroll
                        for (int k = 0; k < 5; ++k)
                            er[k] = EH[(zi-2)%3][j][k] & EH[(zi-1)%3][j][k] & EH[zi%3][j][k];
                        wdilate_row(er, wd);
                        #pragma unroll
                        for (int k = 0; k < 5; ++k) OPN[k] |= wd[k];
                        if (e == dd && j == 1) {
                            #pragma unroll
                            for (int k = 0; k < 5; ++k) EC[k] = er[k];
                        }
                    }
                }
            }
        }
        size_t rowlin = ((size_t)b * DDIM + dd) * HDIM + h;
        unsigned yr[5];
        load_yrow(ysrc + rowlin * YW, yr);
        unsigned* yo = ydst + rowlin * YW;
        unsigned out[5];
        #pragma unroll
        for (int k = 0; k < 5; ++k)
            out[k] = yr[k] & ~(OPN[k] & ~EC[k]);
        *(uint4*)yo = make_uint4(out[0], out[1], out[2], out[3]);
        yo[4] = out[4];
    }
}

// ---------------- final clDice sums ----------------

__global__ void final_reduce_kernel(const float* __restrict__ porig,
                                    const float* __restrict__ pskel,
                                    const int*   __restrict__ target,
                                    const unsigned* __restrict__ yb,
                                    double* __restrict__ partials)
{
    double acc[NQ2];
    #pragma unroll
    for (int q = 0; q < NQ2; ++q) acc[q] = 0.0;
    // 0 = sum(pskel*y_v), 1 = sum(pskel), 2 = sum(y_skel*p_v), 3 = sum(y_skel)

    int tid = blockIdx.x * blockDim.x + threadIdx.x;
    int stride = gridDim.x * blockDim.x;
    for (int g = tid; g < NGRP; g += stride) {
        int i = g * 4;
        float4 ps = *(const float4*)(pskel + i);
        float4 po = *(const float4*)(porig + i);
        int4   tg = *(const int4*)(target + i);
        int w = i % WDIM;
        int rowlin = i / WDIM;
        unsigned word = yb[(size_t)rowlin * YW + (w >> 5)];
        unsigned b4 = (word >> (w & 31)) & 0xFu;
        const float* psp = (const float*)&ps;
        const float* pop = (const float*)&po;
        const int*   tp  = (const int*)&tg;
        #pragma unroll
        for (int j = 0; j < 4; ++j) {
            float yv  = (tp[j] != 0) ? 1.0f : 0.0f;
            float ysk = (float)((b4 >> j) & 1u);
            acc[0] += (double)(psp[j] * yv);
            acc[1] += (double)psp[j];
            acc[2] += (double)(ysk * pop[j]);
            acc[3] += (double)ysk;
        }
    }
    block_reduce_store<NQ2>(acc, partials + (size_t)blockIdx.x * NQ2);
}

// ---------------- finalize ----------------

__global__ void finalize_kernel(const double* __restrict__ p1,
                                const double* __restrict__ p2,
                                float* __restrict__ out)
{
    double acc[NQ1 + NQ2];
    #pragma unroll
    for (int q = 0; q < NQ1 + NQ2; ++q) acc[q] = 0.0;

    for (int b = threadIdx.x; b < NB1; b += 256) {
        #pragma unroll
        for (int q = 0; q < NQ1; ++q) acc[q] += p1[(size_t)b * NQ1 + q];
    }
    for (int b = threadIdx.x; b < NB2; b += 256) {
        #pragma unroll
        for (int q = 0; q < NQ2; ++q) acc[NQ1 + q] += p2[(size_t)b * NQ2 + q];
    }

    __shared__ double smem[NQ1 + NQ2][4];
    int lane = threadIdx.x & 63;
    int wid  = threadIdx.x >> 6;
    #pragma unroll
    for (int q = 0; q < NQ1 + NQ2; ++q) {
        double v = wave_reduce(acc[q]);
        if (lane == 0) smem[q][wid] = v;
    }
    __syncthreads();
    if (threadIdx.x == 0) {
        double a[NQ1 + NQ2];
        #pragma unroll
        for (int q = 0; q < NQ1 + NQ2; ++q)
            a[q] = smem[q][0] + smem[q][1] + smem[q][2] + smem[q][3];

        double ce = a[0] / (double)NVOX;
        double dice = 0.0;
        #pragma unroll
        for (int c = 0; c < 3; ++c) {
            double I = a[1 + c], P = a[4 + c], T = a[7 + c];
            dice += (2.0 * I + SMOOTHF) / (P + T + SMOOTHF);
        }
        dice *= (1.0 / 3.0);
        double base = ce + (1.0 - dice);

        double tprec = a[10] / (a[11] + EPSF);
        double tsens = a[12] / (a[13] + EPSF);
        double cld = 2.0 * tprec * tsens / (tprec + tsens + EPSF);
        out[0] = (float)(base + W_CL * (1.0 - cld));
    }
}

// ---------------- launch ----------------

extern "C" void kernel_launch(void* const* d_in, const int* in_sizes, int n_in,
                              void* d_out, int out_size, void* d_ws, size_t ws_size,
                              hipStream_t stream) {
    const float* logits = (const float*)d_in[0];
    const int*   target = (const int*)d_in[1];

    double* partials1 = (double*)((char*)d_ws + OFF_P1);
    double* partials2 = (double*)((char*)d_ws + OFF_P2);
    float*  porig = (float*)((char*)d_ws + HEADER_BYTES);
    float*  pbA   = porig + NVOX;
    float*  pbB   = pbA + NVOX;
    unsigned* yb0 = (unsigned*)(pbB + NVOX);
    unsigned* yb1 = yb0 + NYW;

    init_kernel<<<NB1, 256, 0, stream>>>(logits, target, porig, partials1);
    ybits_init<<<NYW / 256, 256, 0, stream>>>(target, yb0);

    for (int it = 0; it < ITERS; ++it) {
        const float*    xs = (it == 0) ? porig : ((it % 2 == 1) ? pbA : pbB);
        float*          xd = (it % 2 == 0) ? pbA : pbB;
        const unsigned* ys = (it % 2 == 0) ? yb0 : yb1;
        unsigned*       yd = (it % 2 == 0) ? yb1 : yb0;
        fused_iter<<<F_BLOCKS, 256, 0, stream>>>(xs, xd, ys, yd);
    }
    // after 8 iters: p result in pbB, y result in yb0

    final_reduce_kernel<<<NB2, 256, 0, stream>>>(porig, pbB, target, yb0, partials2);
    finalize_kernel<<<1, 256, 0, stream>>>(partials1, partials2, (float*)d_out);
}

// Round 11
// 618.087 us; speedup vs baseline: 1.3284x; 1.3284x over previous
//
#include <hip/hip_runtime.h>
#include <hip/hip_fp16.h>
#include <math.h>

// Problem constants
#define B_    2
#define DDIM  160
#define HDIM  160
#define WDIM  160
#define DHW   (DDIM*HDIM*WDIM)      // 4,096,000
#define NVOX  (B_*DHW)              // 8,192,000
#define NGRP  (NVOX/4)              // 2,048,000 groups of 4
#define ITERS 8
#define DT    4                     // d-outputs per pool thread

#define SMOOTHF 1e-5
#define EPSF    1e-6
#define W_CL    0.5

// Reduction partials
#define NB1 2048
#define NQ1 10
#define NB2 2048
#define NQ2 4

// Bitpacked y volume
#define NROWS (B_*DDIM*HDIM)        // 51,200 rows
#define YW    8                     // words per row (5 used, 3 pad)
#define NYW   (NROWS*YW)            // 409,600 words

// Fused pool grid: p-blocks then y-blocks
#define P_THREADS (10*HDIM*(DDIM/DT)*B_)   // 128,000
#define P_BLOCKS  (P_THREADS/256)          // 500
#define Y_BLOCKS  (NROWS/256)              // 200
#define F_BLOCKS  (P_BLOCKS + Y_BLOCKS)    // 700

// fp16 pooling pads (data is non-negative -> u16 compare == fp16 compare)
#define PAD_MIN 0x7C00u   // +inf fp16
#define PAD_MAX 0x0000u   // +0, identity for max over non-negative data

// ws layout (bytes)
#define OFF_P1 0
#define OFF_P2 (NB1*NQ1*8)          // 163,840
#define HEADER_BYTES 262144         // 256 KiB

typedef unsigned short u16;

// ---------------- small helpers ----------------

__device__ inline u16 umn(u16 a, u16 b) { return a < b ? a : b; }
__device__ inline u16 umx(u16 a, u16 b) { return a > b ? a : b; }

__device__ inline float us2f(u16 u) {
    __half h; __builtin_memcpy(&h, &u, 2); return __half2float(h);
}
__device__ inline u16 f2us(float f) {
    __half h = __float2half(f); u16 u; __builtin_memcpy(&u, &h, 2); return u;
}

// ---------------- reduction helpers ----------------

__device__ inline double wave_reduce(double v) {
    #pragma unroll
    for (int off = 32; off > 0; off >>= 1)
        v += __shfl_down(v, off, 64);
    return v;
}

template<int NQ>
__device__ inline void block_reduce_store(double* vals, double* out) {
    __shared__ double smem[NQ][4];
    int lane = threadIdx.x & 63;
    int wid  = threadIdx.x >> 6;
    #pragma unroll
    for (int q = 0; q < NQ; ++q) {
        double v = wave_reduce(vals[q]);
        if (lane == 0) smem[q][wid] = v;
    }
    __syncthreads();
    if (threadIdx.x == 0) {
        #pragma unroll
        for (int q = 0; q < NQ; ++q)
            out[q] = smem[q][0] + smem[q][1] + smem[q][2] + smem[q][3];
    }
}

// ---------------- pass 1: softmax / CE / dice partials / p_v ----------------

__global__ void init_kernel(const float* __restrict__ logits,
                            const int*   __restrict__ target,
                            float* __restrict__ porig,
                            u16*   __restrict__ p16,
                            double* __restrict__ partials)
{
    float facc[NQ1];
    #pragma unroll
    for (int q = 0; q < NQ1; ++q) facc[q] = 0.0f;
    // 0=ce, 1..3=intersect_c, 4..6=pred_sum_c, 7..9=targ_sum_c
    // per-thread f32 accumulation (<=16 voxels each), f64 at block level

    int tid = blockIdx.x * blockDim.x + threadIdx.x;
    int stride = gridDim.x * blockDim.x;
    for (int g = tid; g < NGRP; g += stride) {
        int i = g * 4;
        int b = i / DHW;
        int s = i - b * DHW;
        const float* base = logits + (size_t)b * (3 * DHW) + s;
        float4 l0 = *(const float4*)(base);
        float4 l1 = *(const float4*)(base + DHW);
        float4 l2 = *(const float4*)(base + 2 * DHW);
        int4 tg = *(const int4*)(target + i);

        float pv[4];
        const float* a0 = (const float*)&l0;
        const float* a1 = (const float*)&l1;
        const float* a2 = (const float*)&l2;
        const int*   tt = (const int*)&tg;
        #pragma unroll
        for (int j = 0; j < 4; ++j) {
            float x0 = a0[j], x1 = a1[j], x2 = a2[j];
            float m  = fmaxf(x0, fmaxf(x1, x2));
            float e0 = __expf(x0 - m), e1 = __expf(x1 - m), e2 = __expf(x2 - m);
            float sum = e0 + e1 + e2;
            float inv = 1.0f / sum;
            float q0 = e0 * inv, q1 = e1 * inv, q2 = e2 * inv;
            int t = tt[j];
            float lt = (t == 0) ? x0 : ((t == 1) ? x1 : x2);
            float logp_t = (lt - m) - __logf(sum);
            facc[0] += -logp_t;
            facc[4] += q0; facc[5] += q1; facc[6] += q2;
            if (t == 0)      { facc[1] += q0; facc[7] += 1.0f; }
            else if (t == 1) { facc[2] += q1; facc[8] += 1.0f; }
            else             { facc[3] += q2; facc[9] += 1.0f; }
            float p = 1.0f - q0;
            pv[j] = fminf(fmaxf(p, 0.0f), 1.0f);
        }
        *(float4*)(porig + i) = make_float4(pv[0], pv[1], pv[2], pv[3]);
        union { uint2 v; u16 u[4]; } ph;
        #pragma unroll
        for (int j = 0; j < 4; ++j) ph.u[j] = f2us(pv[j]);
        *(uint2*)(p16 + i) = ph.v;
    }
    double acc[NQ1];
    #pragma unroll
    for (int q = 0; q < NQ1; ++q) acc[q] = (double)facc[q];
    block_reduce_store<NQ1>(acc, partials + (size_t)blockIdx.x * NQ1);
}

// ---------------- y bitpack init ----------------

__global__ void ybits_init(const int* __restrict__ target,
                           unsigned* __restrict__ yb)
{
    int tid = blockIdx.x * 256 + threadIdx.x;   // NYW threads exactly
    int k = tid % YW;
    int rowlin = tid / YW;
    unsigned word = 0u;
    if (k < 5) {
        const int* t = target + (size_t)rowlin * WDIM + k * 32;
        #pragma unroll
        for (int q = 0; q < 8; ++q) {
            int4 v = *(const int4*)(t + q * 4);
            if (v.x) word |= 1u << (q * 4 + 0);
            if (v.y) word |= 1u << (q * 4 + 1);
            if (v.z) word |= 1u << (q * 4 + 2);
            if (v.w) word |= 1u << (q * 4 + 3);
        }
    }
    yb[tid] = word;
}

// ---------------- row / bit-row helpers ----------------

// 18-wide fp16 row window [w0-1, w0+16], border filled with pad
__device__ inline void rowload_h(const u16* __restrict__ row, int w0, u16 pad, u16* e) {
    union { uint4 v; u16 u[8]; } a, b;
    a.v = *(const uint4*)(row);
    b.v = *(const uint4*)(row + 8);
    #pragma unroll
    for (int i = 0; i < 8; ++i) { e[1 + i] = a.u[i]; e[9 + i] = b.u[i]; }
    e[0]  = (w0 > 0)         ? row[-1] : pad;
    e[17] = (w0 + 16 < WDIM) ? row[16] : pad;
}

__device__ inline void store16_h(u16* __restrict__ o, const u16* v) {
    union { uint4 q; u16 u[8]; } s0, s1;
    #pragma unroll
    for (int i = 0; i < 8; ++i) { s0.u[i] = v[i]; s1.u[i] = v[8 + i]; }
    *(uint4*)(o)     = s0.q;
    *(uint4*)(o + 8) = s1.q;
}

__device__ inline void load_yrow(const unsigned* __restrict__ base, unsigned* r) {
    uint4 v = *(const uint4*)base;
    r[0] = v.x; r[1] = v.y; r[2] = v.z; r[3] = v.w; r[4] = base[4];
}

__device__ inline void werode_row(const unsigned* r, unsigned* out) {
    #pragma unroll
    for (int k = 0; k < 5; ++k) {
        unsigned l  = (r[k] << 1) | (k > 0 ? (r[k-1] >> 31) : 1u);
        unsigned rt = (r[k] >> 1) | (k < 4 ? (r[k+1] << 31) : 0x80000000u);
        out[k] = r[k] & l & rt;
    }
}

__device__ inline void wdilate_row(const unsigned* r, unsigned* out) {
    #pragma unroll
    for (int k = 0; k < 5; ++k) {
        unsigned l  = (r[k] << 1) | (k > 0 ? (r[k-1] >> 31) : 0u);
        unsigned rt = (r[k] >> 1) | (k < 4 ? (r[k+1] << 31) : 0u);
        out[k] = r[k] | l | rt;
    }
}

// ---------------- fused erode (p fp16 DT-brick + y bitrows) ----------------

__global__ void fused_erode(const u16* __restrict__ x, u16* __restrict__ er,
                            const unsigned* __restrict__ yb, unsigned* __restrict__ eb)
{
    if (blockIdx.x < P_BLOCKS) {
        int tid = blockIdx.x * 256 + threadIdx.x;
        int w16 = tid % 10;
        int t2  = tid / 10;
        int h   = t2 % HDIM;
        int t3  = t2 / HDIM;
        int dc  = t3 % (DDIM / DT);
        int vol = t3 / (DDIM / DT);
        int w0  = w16 * 16;
        int d0  = dc * DT;
        const u16* src = x + (size_t)vol * DHW;
        u16*       dst = er + (size_t)vol * DHW;

        u16 ring[3][16];
        #pragma unroll
        for (int step = 0; step < DT + 2; ++step) {
            int d = d0 - 1 + step;
            u16 cur[16];
            #pragma unroll
            for (int i = 0; i < 16; ++i) cur[i] = PAD_MIN;
            if ((unsigned)d < (unsigned)DDIM) {
                #pragma unroll
                for (int dy = -1; dy <= 1; ++dy) {
                    int y = h + dy;
                    if ((unsigned)y >= (unsigned)HDIM) continue;
                    const u16* row = src + ((size_t)d * HDIM + y) * WDIM + w0;
                    u16 e[18];
                    rowload_h(row, w0, PAD_MIN, e);
                    #pragma unroll
                    for (int i = 0; i < 16; ++i)
                        cur[i] = umn(cur[i], umn(e[i], umn(e[i+1], e[i+2])));
                }
            }
            #pragma unroll
            for (int i = 0; i < 16; ++i) ring[step % 3][i] = cur[i];
            if (step >= 2) {
                int dd = d - 1;
                u16 out[16];
                #pragma unroll
                for (int i = 0; i < 16; ++i)
                    out[i] = umn(ring[0][i], umn(ring[1][i], ring[2][i]));
                store16_h(dst + ((size_t)dd * HDIM + h) * WDIM + w0, out);
            }
        }
    } else {
        int tid = (blockIdx.x - P_BLOCKS) * 256 + threadIdx.x;
        int h  = tid % HDIM;
        int t2 = tid / HDIM;
        int d  = t2 % DDIM;
        int b  = t2 / DDIM;
        unsigned acc[5] = {~0u, ~0u, ~0u, ~0u, ~0u};
        #pragma unroll
        for (int dz = -1; dz <= 1; ++dz) {
            int z = d + dz; if ((unsigned)z >= (unsigned)DDIM) continue;
            #pragma unroll
            for (int dy = -1; dy <= 1; ++dy) {
                int y = h + dy; if ((unsigned)y >= (unsigned)HDIM) continue;
                unsigned r[5], we[5];
                load_yrow(yb + ((size_t)(b * DDIM + z) * HDIM + y) * YW, r);
                werode_row(r, we);
                #pragma unroll
                for (int k = 0; k < 5; ++k) acc[k] &= we[k];
            }
        }
        unsigned* o = eb + (size_t)tid * YW;
        *(uint4*)o = make_uint4(acc[0], acc[1], acc[2], acc[3]);
        o[4] = acc[4];
    }
}

// ---------------- fused open+update (p fp16 DT-brick + y bitrows) ----------------

__global__ void fused_open(const u16* __restrict__ er,
                           const u16* __restrict__ xsrc, u16* __restrict__ xdst,
                           const unsigned* __restrict__ eb, unsigned* __restrict__ yb)
{
    if (blockIdx.x < P_BLOCKS) {
        int tid = blockIdx.x * 256 + threadIdx.x;
        int w16 = tid % 10;
        int t2  = tid / 10;
        int h   = t2 % HDIM;
        int t3  = t2 / HDIM;
        int dc  = t3 % (DDIM / DT);
        int vol = t3 / (DDIM / DT);
        int w0  = w16 * 16;
        int d0  = dc * DT;
        const u16* ers = er + (size_t)vol * DHW;
        const u16* xs  = xsrc + (size_t)vol * DHW;
        u16*       xb  = xdst + (size_t)vol * DHW;

        u16 ring[3][16];
        #pragma unroll
        for (int step = 0; step < DT + 2; ++step) {
            int d = d0 - 1 + step;
            u16 cur[16];
            #pragma unroll
            for (int i = 0; i < 16; ++i) cur[i] = PAD_MAX;
            if ((unsigned)d < (unsigned)DDIM) {
                #pragma unroll
                for (int dy = -1; dy <= 1; ++dy) {
                    int y = h + dy;
                    if ((unsigned)y >= (unsigned)HDIM) continue;
                    const u16* row = ers + ((size_t)d * HDIM + y) * WDIM + w0;
                    u16 e[18];
                    rowload_h(row, w0, PAD_MAX, e);
                    #pragma unroll
                    for (int i = 0; i < 16; ++i)
                        cur[i] = umx(cur[i], umx(e[i], umx(e[i+1], e[i+2])));
                }
            }
            #pragma unroll
            for (int i = 0; i < 16; ++i) ring[step % 3][i] = cur[i];
            if (step >= 2) {
                int dd = d - 1;
                size_t idx = ((size_t)dd * HDIM + h) * WDIM + w0;
                union { uint4 v; u16 u[8]; } ec0, ec1, xv0, xv1;
                ec0.v = *(const uint4*)(ers + idx);
                ec1.v = *(const uint4*)(ers + idx + 8);
                xv0.v = *(const uint4*)(xs + idx);
                xv1.v = *(const uint4*)(xs + idx + 8);
                u16 out[16];
                #pragma unroll
                for (int i = 0; i < 16; ++i) {
                    float of = us2f(umx(ring[0][i], umx(ring[1][i], ring[2][i])));
                    float ef = us2f(i < 8 ? ec0.u[i] : ec1.u[i - 8]);
                    float xf = us2f(i < 8 ? xv0.u[i] : xv1.u[i - 8]);
                    out[i] = f2us(fmaxf(xf - fmaxf(of - ef, 0.0f), 0.0f));
                }
                store16_h(xb + idx, out);
            }
        }
    } else {
        int tid = (blockIdx.x - P_BLOCKS) * 256 + threadIdx.x;
        int h  = tid % HDIM;
        int t2 = tid / HDIM;
        int d  = t2 % DDIM;
        int b  = t2 / DDIM;
        unsigned acc[5] = {0u, 0u, 0u, 0u, 0u};
        unsigned ecen[5];
        #pragma unroll
        for (int dz = -1; dz <= 1; ++dz) {
            int z = d + dz; if ((unsigned)z >= (unsigned)DDIM) continue;
            #pragma unroll
            for (int dy = -1; dy <= 1; ++dy) {
                int y = h + dy; if ((unsigned)y >= (unsigned)HDIM) continue;
                unsigned r[5], wd[5];
                load_yrow(eb + ((size_t)(b * DDIM + z) * HDIM + y) * YW, r);
                if (dz == 0 && dy == 0) {
                    #pragma unroll
                    for (int k = 0; k < 5; ++k) ecen[k] = r[k];
                }
                wdilate_row(r, wd);
                #pragma unroll
                for (int k = 0; k < 5; ++k) acc[k] |= wd[k];
            }
        }
        unsigned* yo = yb + (size_t)tid * YW;
        unsigned yr[5];
        load_yrow(yo, yr);
        unsigned out[5];
        #pragma unroll
        for (int k = 0; k < 5; ++k)
            out[k] = yr[k] & ~(acc[k] & ~ecen[k]);   // x &= ~(opened & ~eroded)
        *(uint4*)yo = make_uint4(out[0], out[1], out[2], out[3]);
        yo[4] = out[4];
    }
}

// ---------------- final clDice sums ----------------

__global__ void final_reduce_kernel(const float* __restrict__ porig,
                                    const u16*   __restrict__ pskel,
                                    const int*   __restrict__ target,
                                    const unsigned* __restrict__ yb,
                                    double* __restrict__ partials)
{
    double acc[NQ2];
    #pragma unroll
    for (int q = 0; q < NQ2; ++q) acc[q] = 0.0;
    // 0 = sum(pskel*y_v), 1 = sum(pskel), 2 = sum(y_skel*p_v), 3 = sum(y_skel)

    int tid = blockIdx.x * blockDim.x + threadIdx.x;
    int stride = gridDim.x * blockDim.x;
    for (int g = tid; g < NGRP; g += stride) {
        int i = g * 4;
        union { uint2 v; u16 u[4]; } ps;
        ps.v = *(const uint2*)(pskel + i);
        float4 po = *(const float4*)(porig + i);
        int4   tg = *(const int4*)(target + i);
        int w = i % WDIM;
        int rowlin = i / WDIM;
        unsigned word = yb[(size_t)rowlin * YW + (w >> 5)];
        unsigned b4 = (word >> (w & 31)) & 0xFu;
        const float* pop = (const float*)&po;
        const int*   tp  = (const int*)&tg;
        #pragma unroll
        for (int j = 0; j < 4; ++j) {
            float psf = us2f(ps.u[j]);
            float yv  = (tp[j] != 0) ? 1.0f : 0.0f;
            float ysk = (float)((b4 >> j) & 1u);
            acc[0] += (double)(psf * yv);
            acc[1] += (double)psf;
            acc[2] += (double)(ysk * pop[j]);
            acc[3] += (double)ysk;
        }
    }
    block_reduce_store<NQ2>(acc, partials + (size_t)blockIdx.x * NQ2);
}

// ---------------- finalize ----------------

__global__ void finalize_kernel(const double* __restrict__ p1,
                                const double* __restrict__ p2,
                                float* __restrict__ out)
{
    double acc[NQ1 + NQ2];
    #pragma unroll
    for (int q = 0; q < NQ1 + NQ2; ++q) acc[q] = 0.0;

    for (int b = threadIdx.x; b < NB1; b += 256) {
        #pragma unroll
        for (int q = 0; q < NQ1; ++q) acc[q] += p1[(size_t)b * NQ1 + q];
    }
    for (int b = threadIdx.x; b < NB2; b += 256) {
        #pragma unroll
        for (int q = 0; q < NQ2; ++q) acc[NQ1 + q] += p2[(size_t)b * NQ2 + q];
    }

    __shared__ double smem[NQ1 + NQ2][4];
    int lane = threadIdx.x & 63;
    int wid  = threadIdx.x >> 6;
    #pragma unroll
    for (int q = 0; q < NQ1 + NQ2; ++q) {
        double v = wave_reduce(acc[q]);
        if (lane == 0) smem[q][wid] = v;
    }
    __syncthreads();
    if (threadIdx.x == 0) {
        double a[NQ1 + NQ2];
        #pragma unroll
        for (int q = 0; q < NQ1 + NQ2; ++q)
            a[q] = smem[q][0] + smem[q][1] + smem[q][2] + smem[q][3];

        double ce = a[0] / (double)NVOX;
        double dice = 0.0;
        #pragma unroll
        for (int c = 0; c < 3; ++c) {
            double I = a[1 + c], P = a[4 + c], T = a[7 + c];
            dice += (2.0 * I + SMOOTHF) / (P + T + SMOOTHF);
        }
        dice *= (1.0 / 3.0);
        double base = ce + (1.0 - dice);

        double tprec = a[10] / (a[11] + EPSF);
        double tsens = a[12] / (a[13] + EPSF);
        double cld = 2.0 * tprec * tsens / (tprec + tsens + EPSF);
        out[0] = (float)(base + W_CL * (1.0 - cld));
    }
}

// ---------------- launch ----------------

extern "C" void kernel_launch(void* const* d_in, const int* in_sizes, int n_in,
                              void* d_out, int out_size, void* d_ws, size_t ws_size,
                              hipStream_t stream) {
    const float* logits = (const float*)d_in[0];
    const int*   target = (const int*)d_in[1];

    double* partials1 = (double*)((char*)d_ws + OFF_P1);
    double* partials2 = (double*)((char*)d_ws + OFF_P2);
    float*  porig = (float*)((char*)d_ws + HEADER_BYTES);
    u16*    pA    = (u16*)(porig + NVOX);
    u16*    pB    = pA + NVOX;
    u16*    erH   = pB + NVOX;
    unsigned* yb0 = (unsigned*)(erH + NVOX);
    unsigned* yb1 = yb0 + NYW;

    init_kernel<<<NB1, 256, 0, stream>>>(logits, target, porig, pA, partials1);
    ybits_init<<<NYW / 256, 256, 0, stream>>>(target, yb0);

    u16* cur = pA;
    u16* nxt = pB;
    for (int it = 0; it < ITERS; ++it) {
        fused_erode<<<F_BLOCKS, 256, 0, stream>>>(cur, erH, yb0, yb1);
        fused_open<<<F_BLOCKS, 256, 0, stream>>>(erH, cur, nxt, yb1, yb0);
        u16* t = cur; cur = nxt; nxt = t;
    }
    // after 8 iters: p result in cur (== pA), y result in yb0

    final_reduce_kernel<<<NB2, 256, 0, stream>>>(porig, cur, target, yb0, partials2);
    finalize_kernel<<<1, 256, 0, stream>>>(partials1, partials2, (float*)d_out);
}